// Round 10
// baseline (30.736 us; speedup 1.0000x reference)
//
#include <hip/hip_runtime.h>

// 3D median filter 3x3x3, stride 1, reflect padding.
// x: (2, 1, 160, 160, 160) fp32 -> same shape. Median = rank 13 (0-based) of 27.
// Round 9: full-width LDS plane ring (7 rows x 160 cols, 6 slots) filled by
// global_load_lds; counted vmcnt(2) + raw s_barrier (T3/T4) so each pair of
// fills has a full iteration in flight. Kills the 3x y-redundant L1-miss
// traffic that R4/R5/R7/R8 counters showed as the real plateau. Compute is
// the hf4 packed-f16 network (4 x-outputs/thread, merge99 shared by 2 z).

typedef __fp16 hf2 __attribute__((ext_vector_type(2)));
typedef __fp16 hf4 __attribute__((ext_vector_type(4)));

#define DEV __device__ __forceinline__

DEV hf4 hmin4(hf4 a, hf4 b) { return __builtin_elementwise_min(a, b); }
DEV hf4 hmax4(hf4 a, hf4 b) { return __builtin_elementwise_max(a, b); }
DEV void ce(hf4& a, hf4& b) { hf4 lo = hmin4(a, b); hf4 hi = hmax4(a, b); a = lo; b = hi; }
DEV hf2 pk2(float a, float b) { return __builtin_amdgcn_cvt_pkrtz(a, b); }
DEV hf4 cat(hf2 a, hf2 b) { return __builtin_shufflevector(a, b, 0, 1, 2, 3); }

DEV void sort3(hf4& a, hf4& b, hf4& c) { ce(a, b); ce(a, c); ce(b, c); }

// Batcher odd-even merges of small sorted sequences (verified exact, rounds 1-8).
DEV void merge21(hf4 a0, hf4 a1, hf4 b0, hf4 z[3]) {
    hf4 e0 = a0, e1 = b0; ce(e0, e1);
    z[0] = e0; z[1] = a1; z[2] = e1; ce(z[1], z[2]);
}
DEV void merge22(hf4 a0, hf4 a1, hf4 b0, hf4 b1, hf4 z[4]) {
    hf4 p0 = a0, p1 = b0; ce(p0, p1);
    hf4 q0 = a1, q1 = b1; ce(q0, q1);
    z[0] = p0; z[1] = q0; z[2] = p1; ce(z[1], z[2]); z[3] = q1;
}
DEV void merge31(hf4 a0, hf4 a1, hf4 a2, hf4 b0, hf4 z[4]) {
    hf4 e[3]; merge21(a0, a2, b0, e);
    z[0] = e[0]; z[1] = a1; z[2] = e[1]; ce(z[1], z[2]); z[3] = e[2];
}
DEV void merge32(hf4 a0, hf4 a1, hf4 a2, hf4 b0, hf4 b1, hf4 z[5]) {
    hf4 e[3]; merge21(a0, a2, b0, e);
    hf4 o0 = a1, o1 = b1; ce(o0, o1);
    z[0] = e[0];
    z[1] = o0; z[2] = e[1]; ce(z[1], z[2]);
    z[3] = o1; z[4] = e[2]; ce(z[3], z[4]);
}
DEV void merge33(const hf4 a[3], const hf4 b[3], hf4 z[6]) {
    hf4 e[4]; merge22(a[0], a[2], b[0], b[2], e);
    hf4 o0 = a[1], o1 = b[1]; ce(o0, o1);
    z[0] = e[0];
    z[1] = o0; z[2] = e[1]; ce(z[1], z[2]);
    z[3] = o1; z[4] = e[2]; ce(z[3], z[4]);
    z[5] = e[3];
}
DEV void merge63(const hf4 a[6], const hf4 b[3], hf4 z[9]) {
    hf4 e[5]; merge32(a[0], a[2], a[4], b[0], b[2], e);
    hf4 o[4]; merge31(a[1], a[3], a[5], b[1], o);
    z[0] = e[0];
    z[1] = o[0]; z[2] = e[1]; ce(z[1], z[2]);
    z[3] = o[1]; z[4] = e[2]; ce(z[3], z[4]);
    z[5] = o[2]; z[6] = e[3]; ce(z[5], z[6]);
    z[7] = o[3]; z[8] = e[4]; ce(z[7], z[8]);
}
DEV void merge44(const hf4 a[4], const hf4 b[4], hf4 z[8]) {
    hf4 e[4]; merge22(a[0], a[2], b[0], b[2], e);
    hf4 o[4]; merge22(a[1], a[3], b[1], b[3], o);
    z[0] = e[0];
    z[1] = o[0]; z[2] = e[1]; ce(z[1], z[2]);
    z[3] = o[1]; z[4] = e[2]; ce(z[3], z[4]);
    z[5] = o[2]; z[6] = e[3]; ce(z[5], z[6]);
    z[7] = o[3];
}
DEV void merge55(const hf4 a[5], const hf4 b[5], hf4 z[10]) {
    hf4 ae[3] = {a[0], a[2], a[4]}, be[3] = {b[0], b[2], b[4]};
    hf4 e[6]; merge33(ae, be, e);
    hf4 o[4]; merge22(a[1], a[3], b[1], b[3], o);
    z[0] = e[0];
    z[1] = o[0]; z[2] = e[1]; ce(z[1], z[2]);
    z[3] = o[1]; z[4] = e[2]; ce(z[3], z[4]);
    z[5] = o[2]; z[6] = e[3]; ce(z[5], z[6]);
    z[7] = o[3]; z[8] = e[4]; ce(z[7], z[8]);
    z[9] = e[5];
}
DEV void merge99(const hf4 a[9], const hf4 b[9], hf4 z[18]) {
    hf4 ae[5] = {a[0], a[2], a[4], a[6], a[8]};
    hf4 be[5] = {b[0], b[2], b[4], b[6], b[8]};
    hf4 e[10]; merge55(ae, be, e);
    hf4 ao[4] = {a[1], a[3], a[5], a[7]};
    hf4 bo[4] = {b[1], b[3], b[5], b[7]};
    hf4 o[8]; merge44(ao, bo, o);
    z[0] = e[0];
#pragma unroll
    for (int i = 0; i < 8; i++) {
        z[2 * i + 1] = o[i];
        z[2 * i + 2] = e[i + 1];
        ce(z[2 * i + 1], z[2 * i + 2]);
    }
    z[17] = e[9];
}

// rank-13-of-27 from merged-18 E and sorted-9 R (verified exact in round 1):
DEV hf4 sel13(const hf4 E[18], const hf4 R[9]) {
    hf4 m = E[13];
#pragma unroll
    for (int i = 0; i < 9; i++) m = hmin4(m, hmax4(R[i], E[12 - i]));
    return m;
}

constexpr int Bb = 2, Dd = 160, Hh = 160, Ww = 160;
constexpr int HW = Hh * Ww;          // 25600
constexpr int STRIP = 5;             // output rows per block
constexpr int NSTRIP = Hh / STRIP;   // 32
constexpr int CH = 10;               // z-chunk per block
constexpr int NCH = Dd / CH;         // 16
constexpr int TROWS = STRIP + 2;     // 7 (y-halo)
constexpr int PLANEF = TROWS * Ww;   // 1120 floats per plane tile
constexpr int NRING = 6;             // LDS plane ring slots
constexpr int NBLK = Bb * NCH * NSTRIP;  // 1024 blocks

typedef __attribute__((address_space(1))) const unsigned int gas_u32;
typedef __attribute__((address_space(3))) unsigned int las_u32;

// counted wait + raw barrier (T3/T4): vmcnt(2) is <= the exact per-wave
// allowance at every wait site (verified against fill/store issue counts),
// so the consumed pair is always resident while the next pair stays in flight
// for a full iteration. sched_barrier(0) fences both sides (rule #18).
#define WAIT_BARRIER()                                               \
    do {                                                             \
        asm volatile("s_waitcnt vmcnt(2) lgkmcnt(0)" ::: "memory");  \
        __builtin_amdgcn_sched_barrier(0);                           \
        __builtin_amdgcn_s_barrier();                                \
        __builtin_amdgcn_sched_barrier(0);                           \
    } while (0)

__global__ __launch_bounds__(256, 4) void MedianPool3d_68994354642979_kernel(
    const float* __restrict__ in, float* __restrict__ out) {
    __shared__ float lds[NRING * PLANEF];  // 26,880 B

    const int tid = threadIdx.x;
    int bid = blockIdx.x;
    const int ty = bid % NSTRIP; bid /= NSTRIP;
    const int zc = bid % NCH;
    const int b  = bid / NCH;
    const int z0 = zc * CH;
    const int y0 = ty * STRIP;

    const float* base = in + (size_t)b * Dd * HW;
    float* ob = out + (size_t)b * Dd * HW;

    // Fill plane m (global plane z0-1+m, z-reflected) into ring slot m%NRING.
    // 280 16B-chunks: every thread 1, threads 0..23 a 2nd (wave0 only).
    auto fill = [&](int m) {
        int p = z0 - 1 + m;
        p = (p < 0) ? 1 : ((p > Dd - 1) ? Dd - 2 : p);  // z reflect (±1 max)
        const float* pp = base + (size_t)p * HW;
        float* ldsb = &lds[(m % NRING) * PLANEF];
        {
            int row = tid / 40, c4 = tid % 40;
            int gy = y0 - 1 + row;
            gy = (gy < 0) ? 1 : ((gy > Hh - 1) ? Hh - 2 : gy);  // y reflect
            const float* src = pp + gy * Ww + c4 * 4;
            float* dst = ldsb + (size_t)(tid & ~63) * 4;  // wave-uniform base
            __builtin_amdgcn_global_load_lds((gas_u32*)src, (las_u32*)dst, 16, 0, 0);
        }
        if (tid < 24) {  // chunks 256..279 (row 6, cols 64..159)
            int c = 256 + tid;
            int c4 = c % 40;
            int gy = y0 + 5;
            gy = (gy > Hh - 1) ? Hh - 2 : gy;
            const float* src = pp + gy * Ww + c4 * 4;
            float* dst = ldsb + 256 * 4;
            __builtin_amdgcn_global_load_lds((gas_u32*)src, (las_u32*)dst, 16, 0, 0);
        }
    };

    // Compute site: 200 active threads -> (q, ly), 4 x-outputs each.
    const int q = tid % 40;
    const int ly = tid / 40;      // 0..4 active
    const int x0 = q * 4;
    const int cLi = (q == 0) ? 1 : (x0 - 1);          // x reflect via LDS col
    const int cRi = (q == 39) ? (Ww - 2) : (x0 + 4);

    auto sortp = [&](int m, hf4(&M)[9]) {
        const float* tb = &lds[(m % NRING) * PLANEF];
        hf4 r[3][3];
#pragma unroll
        for (int i = 0; i < 3; i++) {
            const float* rp = tb + (ly + i) * Ww;
            float4 v = *reinterpret_cast<const float4*>(rp + x0);  // ds_read_b128
            float a = rp[cLi], d = rp[cRi];
            hf2 pAL = pk2(a, v.x);
            hf2 pAC = pk2(v.x, v.y);
            hf2 pSH = pk2(v.y, v.z);
            hf2 pBC = pk2(v.z, v.w);
            hf2 pBR = pk2(v.w, d);
            r[i][0] = cat(pAL, pSH);
            r[i][1] = cat(pAC, pBC);
            r[i][2] = cat(pSH, pBR);
            sort3(r[i][0], r[i][1], r[i][2]);
        }
        hf4 s6[6]; merge33(r[0], r[1], s6);
        merge63(s6, r[2], M);
    };

    // Prologue: issue pairs P0{m0,m1}, P1{m2,m3}, P2{m4,m5}; wait P0; sort m0,m1.
    fill(0); fill(1);
    fill(2); fill(3);
    fill(4); fill(5);
    WAIT_BARRIER();

    hf4 SS[4][9];
    if (tid < 200) { sortp(0, SS[0]); sortp(1, SS[1]); }

#pragma unroll
    for (int j = 0; j < CH / 2; j++) {
        WAIT_BARRIER();  // pair j+1 (planes m=2j+2, 2j+3) resident; slot 2j%6 free

        if (2 * j + 7 <= CH + 1) { fill(2 * j + 6); fill(2 * j + 7); }  // pair j+3

        if (tid < 200) {
            const int sA = (2 * j) & 3;      // S[z-1]
            const int sB = (2 * j + 1) & 3;  // S[z]
            const int sC = (2 * j + 2) & 3;  // S[z+1]
            const int sD = (2 * j + 3) & 3;  // S[z+2]
            sortp(2 * j + 2, SS[sC]);
            sortp(2 * j + 3, SS[sD]);

            hf4 E[18];
            merge99(SS[sB], SS[sC], E);   // shared pair (z, z+1) -> used twice
            hf4 m0 = sel13(E, SS[sA]);    // output z   : third plane z-1
            hf4 m1 = sel13(E, SS[sD]);    // output z+1 : third plane z+2

            const int z = z0 + 2 * j;
            float* o0 = ob + (size_t)z * HW + (y0 + ly) * Ww + x0;  // 16B-aligned
            float* o1 = o0 + HW;
            *reinterpret_cast<float4*>(o0) =
                make_float4((float)m0.x, (float)m0.y, (float)m0.z, (float)m0.w);
            *reinterpret_cast<float4*>(o1) =
                make_float4((float)m1.x, (float)m1.y, (float)m1.z, (float)m1.w);
        }
    }
}

extern "C" void kernel_launch(void* const* d_in, const int* in_sizes, int n_in,
                              void* d_out, int out_size, void* d_ws, size_t ws_size,
                              hipStream_t stream) {
    const float* x = (const float*)d_in[0];
    float* out = (float*)d_out;
    MedianPool3d_68994354642979_kernel<<<NBLK, 256, 0, stream>>>(x, out);
}